// Round 16
// baseline (306.116 us; speedup 1.0000x reference)
//
#include <hip/hip_runtime.h>

#define N_NODES 50000
#define N_EDGES 800000
#define DIM 128
#define NLAYERS 3
#define NCLASSES 6
#define NGRAPHS 64
#define BN_EPS 1e-5f

#define SCAN_BLK 256
#define SCAN_NB ((N_NODES + SCAN_BLK - 1) / SCAN_BLK)  // 196

#define POOL_CHUNKS 8
#define NPART 16

#define FILL_GRPS 8
#define FILL_BPG 128
#define NODES_PER_GRP ((N_NODES + FILL_GRPS - 1) / FILL_GRPS)  // 6250

typedef unsigned short ushort_t;
typedef unsigned int uint_t;
using bf16x8 = __attribute__((ext_vector_type(8))) short;
using f32x4 = __attribute__((ext_vector_type(4))) float;

__device__ __forceinline__ float bf2f(ushort_t b) {
  return __uint_as_float(((uint_t)b) << 16);
}
__device__ __forceinline__ ushort_t f2bf(float f) {  // round-to-nearest-even
  uint_t u = __float_as_uint(f);
  u += 0x7fffu + ((u >> 16) & 1u);
  return (ushort_t)(u >> 16);
}

// ---------------- CSR build ----------------

__global__ void k_count(const int* __restrict__ dst, int* __restrict__ cnt) {
  int e = blockIdx.x * blockDim.x + threadIdx.x;
  if (e < N_EDGES) atomicAdd(&cnt[dst[e]], 1);
}

__global__ void k_scan_a(const int* __restrict__ cnt, int* __restrict__ incl,
                         int* __restrict__ bsum) {
  __shared__ int s[SCAN_BLK];
  int i = blockIdx.x * SCAN_BLK + threadIdx.x;
  int v = (i < N_NODES) ? cnt[i] : 0;
  s[threadIdx.x] = v;
  __syncthreads();
  for (int off = 1; off < SCAN_BLK; off <<= 1) {
    int t = (threadIdx.x >= off) ? s[threadIdx.x - off] : 0;
    __syncthreads();
    s[threadIdx.x] += t;
    __syncthreads();
  }
  if (i < N_NODES) incl[i] = s[threadIdx.x];
  if (threadIdx.x == SCAN_BLK - 1) bsum[blockIdx.x] = s[SCAN_BLK - 1];
}

__global__ void k_scan_b(const int* __restrict__ bsum, int* __restrict__ boff) {
  __shared__ int s[SCAN_BLK];
  int t = threadIdx.x;
  int v = (t < SCAN_NB) ? bsum[t] : 0;
  s[t] = v;
  __syncthreads();
  for (int off = 1; off < SCAN_BLK; off <<= 1) {
    int u = (t >= off) ? s[t - off] : 0;
    __syncthreads();
    s[t] += u;
    __syncthreads();
  }
  boff[t] = s[t] - v;
}

__global__ void k_scan_c(const int* __restrict__ cnt, const int* __restrict__ incl,
                         const int* __restrict__ boff, int* __restrict__ row_ptr,
                         int* __restrict__ cursor, float* __restrict__ degf) {
  int i = blockIdx.x * SCAN_BLK + threadIdx.x;
  if (i < N_NODES) {
    int ex = incl[i] - cnt[i] + boff[blockIdx.x];
    row_ptr[i] = ex;
    cursor[i] = ex;
    degf[i] = (float)max(cnt[i], 1);
  }
  if (i == 0) row_ptr[N_NODES] = N_EDGES;
}

// group-partitioned fill with LDS queue compaction: matching edges are
// compacted in LDS, then drained in dense 256-entry rounds so cursor
// atomics + col stores issue with full 64-lane waves.
__global__ void k_fill4(const int* __restrict__ src, const int* __restrict__ dst,
                        int* __restrict__ cursor, int* __restrict__ col) {
  __shared__ int qd[1024], qs[1024];
  __shared__ int qn;
  int tid = threadIdx.x;
  int grp = blockIdx.x & (FILL_GRPS - 1);
  int blk = blockIdx.x >> 3;
  int lo = grp * NODES_PER_GRP;
  int hi = min(lo + NODES_PER_GRP, N_NODES);
  int per = (N_EDGES + FILL_BPG - 1) / FILL_BPG;  // 6250
  int es = blk * per, ee = min(es + per, N_EDGES);
  if (tid == 0) qn = 0;
  __syncthreads();
  for (int base = es; base < ee; base += (int)blockDim.x) {
    int e = base + tid;
    int d = 0, s = 0;
    bool m = false;
    if (e < ee) {
      d = dst[e];
      if (d >= lo && d < hi) {
        m = true;
        s = src[e];
      }
    }
    if (m) {
      int pos = atomicAdd(&qn, 1);
      qd[pos] = d;
      qs[pos] = s;
    }
    __syncthreads();
    if (qn >= 768) {
      int n = qn & ~255;  // drain a multiple of 256, keep <256 remainder
      for (int i = tid; i < n; i += 256) {
        int pos = atomicAdd(&cursor[qd[i]], 1);
        col[pos] = qs[i];
      }
      __syncthreads();
      int rem = qn - n;
      int td = 0, ts2 = 0;
      if (tid < rem) {
        td = qd[n + tid];
        ts2 = qs[n + tid];
      }
      __syncthreads();
      if (tid < rem) {
        qd[tid] = td;
        qs[tid] = ts2;
      }
      if (tid == 0) qn = rem;
      __syncthreads();
    }
  }
  for (int i = tid; i < qn; i += 256) {
    int pos = atomicAdd(&cursor[qd[i]], 1);
    col[pos] = qs[i];
  }
}

// ---------------- weight prep: split hi/lo bf16, frag-order permute ----------------
// W2 layout (ushort): [l][kstep 0..7][part 0..1][q 0..3][c 0..127][kk8 0..7]
__global__ void k_wt2(const float* __restrict__ Wl, const float* __restrict__ Wr,
                      ushort_t* __restrict__ W2) {
  int i = blockIdx.x * blockDim.x + threadIdx.x;  // 3*8*4*128 = 12288
  if (i >= NLAYERS * 8 * 4 * 128) return;
  int c = i & 127;
  int q = (i >> 7) & 3;
  int ks = (i >> 9) & 7;
  int l = i >> 12;
  int kbase = ks * 32 + q * 8;
  size_t obase = (size_t)l * 65536 + ks * 8192 + q * 1024 + c * 8;
#pragma unroll
  for (int kk = 0; kk < 8; ++kk) {
    int k = kbase + kk;
    float w = (k < DIM) ? Wl[(size_t)l * DIM * DIM + c * DIM + k]
                        : Wr[(size_t)l * DIM * DIM + c * DIM + (k - DIM)];
    ushort_t hi = f2bf(w);
    float lo = w - bf2f(hi);
    W2[obase + kk] = hi;
    W2[obase + 4096 + kk] = f2bf(lo);  // part 1 offset = 4*1024
  }
}

// fp32 -> bf16 convert (input x)
__global__ void k_tobf16(const float* __restrict__ x, ushort_t* __restrict__ xb) {
  int i4 = blockIdx.x * blockDim.x + threadIdx.x;
  if (i4 >= N_NODES * DIM / 4) return;
  float4 v = ((const float4*)x)[i4];
  ushort4 o;
  o.x = f2bf(v.x);
  o.y = f2bf(v.y);
  o.z = f2bf(v.z);
  o.w = f2bf(v.w);
  ((ushort4*)xb)[i4] = o;
}

// ---------------- per-layer kernels ----------------

__device__ __forceinline__ void acc_row(uint4 v, float* a) {
  a[0] += bf2f((ushort_t)(v.x & 0xffffu));
  a[1] += bf2f((ushort_t)(v.x >> 16));
  a[2] += bf2f((ushort_t)(v.y & 0xffffu));
  a[3] += bf2f((ushort_t)(v.y >> 16));
  a[4] += bf2f((ushort_t)(v.z & 0xffffu));
  a[5] += bf2f((ushort_t)(v.z >> 16));
  a[6] += bf2f((ushort_t)(v.w & 0xffffu));
  a[7] += bf2f((ushort_t)(v.w >> 16));
}

// one wave per node; 16 lanes per row (uint4 = 16B), 4 neighbors concurrent;
// predicated 4-deep tail (remainder edges loaded in ONE batched round).
__global__ void k_gather4(const ushort_t* __restrict__ xb, const int* __restrict__ row_ptr,
                          const int* __restrict__ col, const float* __restrict__ degf,
                          ushort_t* __restrict__ aggb) {
  int wid = threadIdx.x >> 6, lane = threadIdx.x & 63;
  int n = blockIdx.x * 4 + wid;
  if (n >= N_NODES) return;
  int beg = row_ptr[n], end = row_ptr[n + 1];
  int sub = lane >> 4;  // 0..3: neighbor sub-stream
  int c16 = lane & 15;  // uint4 index within row
  const uint4* x4 = (const uint4*)xb;
  float a[8] = {0.f, 0.f, 0.f, 0.f, 0.f, 0.f, 0.f, 0.f};
  int p = beg + sub;
  for (; p + 12 < end; p += 16) {
    int c[4];
#pragma unroll
    for (int u = 0; u < 4; ++u) c[u] = col[p + 4 * u];
    uint4 v[4];
#pragma unroll
    for (int u = 0; u < 4; ++u) v[u] = x4[(size_t)c[u] * 16 + c16];
#pragma unroll
    for (int u = 0; u < 4; ++u) acc_row(v[u], a);
  }
  if (p < end) {  // predicated batched tail: up to 4 loads in flight
    int c[4];
#pragma unroll
    for (int u = 0; u < 4; ++u) {
      int pp = p + 4 * u;
      c[u] = (pp < end) ? col[pp] : -1;
    }
    uint4 v[4];
#pragma unroll
    for (int u = 0; u < 4; ++u) {
      int cc = (c[u] < 0) ? 0 : c[u];
      v[u] = x4[(size_t)cc * 16 + c16];
    }
#pragma unroll
    for (int u = 0; u < 4; ++u)
      if (c[u] >= 0) acc_row(v[u], a);
  }
#pragma unroll
  for (int u = 0; u < 8; ++u) {
    a[u] += __shfl_xor(a[u], 16);
    a[u] += __shfl_xor(a[u], 32);
  }
  if (sub == 0) {
    float inv = 1.0f / degf[n];
    uint4 o;
    o.x = (uint_t)f2bf(a[0] * inv) | ((uint_t)f2bf(a[1] * inv) << 16);
    o.y = (uint_t)f2bf(a[2] * inv) | ((uint_t)f2bf(a[3] * inv) << 16);
    o.z = (uint_t)f2bf(a[4] * inv) | ((uint_t)f2bf(a[5] * inv) << 16);
    o.w = (uint_t)f2bf(a[6] * inv) | ((uint_t)f2bf(a[7] * inv) << 16);
    ((uint4*)aggb)[(size_t)n * 16 + c16] = o;
  }
}

// MFMA GEMM + fused BN stats (round-11 structure: 2 K-steps/stage via regular
// vector loads, per-wave epilogue, shuffle+LDS BN partials, bf16 h output).
__global__ __launch_bounds__(256) void k_mfma3(
    const ushort_t* __restrict__ aggb, const ushort_t* __restrict__ xb,
    const ushort_t* __restrict__ W2l, const float* __restrict__ bl,
    ushort_t* __restrict__ hb, float* __restrict__ sums_part) {
  __shared__ ushort_t Bs[16384];   // 32 KB: two ksteps [kh][part][q][c][8]
  __shared__ float Es[4][16][65];  // 16.6 KB per-wave transpose
  __shared__ float lsums[4][256];  // 4 KB BN partials

  int tid = threadIdx.x;
  int wave = tid >> 6, lane = tid & 63;
  int rw = blockIdx.x * 64 + wave * 16;
  int lr = lane & 15;  // frag row / frag col
  int q = lane >> 4;   // 0..3 (k-chunk)
  int rowA = rw + lr;
  if (rowA > N_NODES - 1) rowA = N_NODES - 1;  // clamp; stores/stats guarded

  f32x4 acc[8];
#pragma unroll
  for (int c = 0; c < 8; ++c) acc[c] = (f32x4){0.f, 0.f, 0.f, 0.f};

#pragma unroll 1
  for (int kp = 0; kp < 4; ++kp) {
    const uint4* wsrc = (const uint4*)(W2l + (size_t)kp * 16384);
#pragma unroll
    for (int it = 0; it < 8; ++it)
      ((uint4*)Bs)[it * 256 + tid] = wsrc[it * 256 + tid];
    __syncthreads();
#pragma unroll
    for (int kh = 0; kh < 2; ++kh) {
      int ks = kp * 2 + kh;
      const ushort_t* Asrc = (ks < 4) ? aggb : xb;
      int koff = (ks & 3) * 32 + q * 8;
      bf16x8 af = *(const bf16x8*)(Asrc + (size_t)rowA * DIM + koff);
      const ushort_t* bbase = Bs + kh * 8192 + q * 1024;
#pragma unroll
      for (int cf = 0; cf < 8; ++cf) {
        int ci = cf * 16 + lr;
        bf16x8 bh = *(const bf16x8*)(bbase + ci * 8);
        bf16x8 bo = *(const bf16x8*)(bbase + 4096 + ci * 8);
        acc[cf] = __builtin_amdgcn_mfma_f32_16x16x32_bf16(af, bh, acc[cf], 0, 0, 0);
        acc[cf] = __builtin_amdgcn_mfma_f32_16x16x32_bf16(af, bo, acc[cf], 0, 0, 0);
      }
    }
    __syncthreads();
  }

  // epilogue: per-wave transpose -> bf16 store + column stats
  float ts[2][4] = {{0.f, 0.f, 0.f, 0.f}, {0.f, 0.f, 0.f, 0.f}};
  float tq[2][4] = {{0.f, 0.f, 0.f, 0.f}, {0.f, 0.f, 0.f, 0.f}};
#pragma unroll
  for (int colhalf = 0; colhalf < 2; ++colhalf) {
#pragma unroll
    for (int cf2 = 0; cf2 < 4; ++cf2) {
      f32x4 a = acc[colhalf * 4 + cf2];
#pragma unroll
      for (int i = 0; i < 4; ++i) Es[wave][q * 4 + i][cf2 * 16 + lr] = a[i];
    }
#pragma unroll
    for (int it = 0; it < 4; ++it) {
      int idx = it * 64 + lane;
      int r = idx >> 4, c4 = idx & 15;
      int n = rw + r;
      if (n < N_NODES) {
        int j = colhalf * 64 + c4 * 4;
        float4 v = *(float4*)&Es[wave][r][c4 * 4];
        v.x += bl[j];
        v.y += bl[j + 1];
        v.z += bl[j + 2];
        v.w += bl[j + 3];
        ts[colhalf][0] += v.x;
        ts[colhalf][1] += v.y;
        ts[colhalf][2] += v.z;
        ts[colhalf][3] += v.w;
        tq[colhalf][0] += v.x * v.x;
        tq[colhalf][1] += v.y * v.y;
        tq[colhalf][2] += v.z * v.z;
        tq[colhalf][3] += v.w * v.w;
        ushort4 o;
        o.x = f2bf(v.x);
        o.y = f2bf(v.y);
        o.z = f2bf(v.z);
        o.w = f2bf(v.w);
        *(ushort4*)(hb + (size_t)n * DIM + j) = o;
      }
    }
  }
  // BN partials: q-group shuffle reduce -> plain LDS -> 256 atomics/block
#pragma unroll
  for (int ch = 0; ch < 2; ++ch)
#pragma unroll
    for (int u = 0; u < 4; ++u) {
      ts[ch][u] += __shfl_xor(ts[ch][u], 16);
      ts[ch][u] += __shfl_xor(ts[ch][u], 32);
      tq[ch][u] += __shfl_xor(tq[ch][u], 16);
      tq[ch][u] += __shfl_xor(tq[ch][u], 32);
    }
  if (lane < 16) {
#pragma unroll
    for (int ch = 0; ch < 2; ++ch)
#pragma unroll
      for (int u = 0; u < 4; ++u) {
        int j = ch * 64 + lr * 4 + u;
        lsums[wave][j] = ts[ch][u];
        lsums[wave][128 + j] = tq[ch][u];
      }
  }
  __syncthreads();
  float tot = lsums[0][tid] + lsums[1][tid] + lsums[2][tid] + lsums[3][tid];
  atomicAdd(&sums_part[(blockIdx.x & (NPART - 1)) * 256 + tid], tot);
}

// fold partitioned BN sums into scale/shift; self-clear sums_part for next layer
__global__ void k_bnfin(float* __restrict__ sums_part, const float* __restrict__ gamma,
                        const float* __restrict__ beta, float* __restrict__ bnsc) {
  int j = threadIdx.x;  // 128
  float s = 0.f, q = 0.f;
  for (int p = 0; p < NPART; ++p) {
    s += sums_part[p * 256 + j];
    q += sums_part[p * 256 + 128 + j];
    sums_part[p * 256 + j] = 0.f;
    sums_part[p * 256 + 128 + j] = 0.f;
  }
  float mu = s * (1.0f / N_NODES);
  float var = q * (1.0f / N_NODES) - mu * mu;
  float sc = gamma[j] * rsqrtf(var + BN_EPS);
  bnsc[j] = sc;
  bnsc[128 + j] = beta[j] - mu * sc;
}

// normalize + relu: bf16 h -> bf16 x
__global__ void k_bn_apply2(const ushort_t* __restrict__ hb, const float* __restrict__ bnsc,
                            ushort_t* __restrict__ xb) {
  int i4 = blockIdx.x * blockDim.x + threadIdx.x;
  if (i4 >= N_NODES * DIM / 4) return;
  int j0 = (i4 * 4) & (DIM - 1);
  ushort4 v = ((const ushort4*)hb)[i4];
  float o[4] = {bf2f(v.x), bf2f(v.y), bf2f(v.z), bf2f(v.w)};
  ushort4 r;
#pragma unroll
  for (int u = 0; u < 4; ++u) {
    int j = j0 + u;
    o[u] = fmaxf(fmaf(o[u], bnsc[j], bnsc[128 + j]), 0.f);
  }
  r.x = f2bf(o[0]);
  r.y = f2bf(o[1]);
  r.z = f2bf(o[2]);
  r.w = f2bf(o[3]);
  ((ushort4*)xb)[i4] = r;
}

// ---------------- pooling + head ----------------

__global__ void k_gbounds(const int* __restrict__ batch, int* __restrict__ gstart) {
  int t = threadIdx.x;
  if (t > NGRAPHS) return;
  if (t == NGRAPHS) {
    gstart[NGRAPHS] = N_NODES;
    return;
  }
  int lo = 0, hi = N_NODES;
  while (lo < hi) {
    int mid = (lo + hi) >> 1;
    if (batch[mid] < t) lo = mid + 1;
    else hi = mid;
  }
  gstart[t] = lo;
}

// pool over the LAST layer from bf16 h + bnsc (BN+ReLU fused in).
__global__ void k_pool4(const ushort_t* __restrict__ hb, const float* __restrict__ bnsc,
                        const int* __restrict__ gstart, float* __restrict__ pooled) {
  int g = blockIdx.x >> 3;
  int ck = blockIdx.x & 7;
  int s = gstart[g], e = gstart[g + 1];
  int len = e - s;
  int per = (len + POOL_CHUNKS - 1) / POOL_CHUNKS;
  int rs = s + ck * per;
  int re = min(rs + per, e);
  int j2 = threadIdx.x & 63;  // uint (2 feats)
  int rg = threadIdx.x >> 6;  // 0..3
  const uint_t* h1 = (const uint_t*)hb;
  float sc0 = bnsc[2 * j2], sh0 = bnsc[128 + 2 * j2];
  float sc1 = bnsc[2 * j2 + 1], sh1 = bnsc[128 + 2 * j2 + 1];
  float ax = 0.f, ay = 0.f;
  for (int r = rs + rg; r < re; r += 4) {
    uint_t v = h1[(size_t)r * 64 + j2];
    ax += fmaxf(fmaf(bf2f((ushort_t)(v & 0xffffu)), sc0, sh0), 0.f);
    ay += fmaxf(fmaf(bf2f((ushort_t)(v >> 16)), sc1, sh1), 0.f);
  }
  __shared__ float sred[4][DIM];
  sred[rg][2 * j2] = ax;
  sred[rg][2 * j2 + 1] = ay;
  __syncthreads();
  if (rg < 2) {
    int j = rg * 64 + j2;
    float v = sred[0][j] + sred[1][j] + sred[2][j] + sred[3][j];
    atomicAdd(&pooled[g * DIM + j], v);
  }
}

// one block per graph: pm staged in LDS; shuffle-reduce MLP head.
__global__ void k_head2(const float* __restrict__ pooled, const int* __restrict__ gstart,
                        const float* __restrict__ W1, const float* __restrict__ b1,
                        const float* __restrict__ W2, const float* __restrict__ b2,
                        float* __restrict__ out) {
  int g = blockIdx.x;
  int tid = threadIdx.x;
  __shared__ float pm[DIM];
  __shared__ float hid[64];
  float inv = 1.0f / fmaxf((float)(gstart[g + 1] - gstart[g]), 1.0f);
  if (tid < DIM) pm[tid] = pooled[g * DIM + tid] * inv;
  __syncthreads();
  {
    int m = tid >> 2, part = tid & 3;
    const float* w = W1 + m * DIM + part * 32;
    const float* pp = pm + part * 32;
    float acc = 0.f;
#pragma unroll
    for (int k = 0; k < 32; ++k) acc += pp[k] * w[k];
    acc += __shfl_down(acc, 1);
    acc += __shfl_down(acc, 2);
    if (part == 0) hid[m] = fmaxf(acc + b1[m], 0.f);
  }
  __syncthreads();
  if (tid < NCLASSES * 8) {
    int c = tid >> 3, pp8 = tid & 7;
    const float* w = W2 + c * 64 + pp8 * 8;
    const float* hh = hid + pp8 * 8;
    float acc = 0.f;
#pragma unroll
    for (int k = 0; k < 8; ++k) acc += hh[k] * w[k];
    acc += __shfl_down(acc, 1);
    acc += __shfl_down(acc, 2);
    acc += __shfl_down(acc, 4);
    if (pp8 == 0) out[g * NCLASSES + c] = acc + b2[c];
  }
}

// ---------------- launch ----------------

extern "C" void kernel_launch(void* const* d_in, const int* in_sizes, int n_in,
                              void* d_out, int out_size, void* d_ws, size_t ws_size,
                              hipStream_t stream) {
  const float* x = (const float*)d_in[0];
  const int* edge = (const int*)d_in[1];
  const int* batch = (const int*)d_in[2];
  const float* Wl = (const float*)d_in[3];
  const float* bl = (const float*)d_in[4];
  const float* Wr = (const float*)d_in[5];
  const float* gamma = (const float*)d_in[6];
  const float* beta = (const float*)d_in[7];
  const float* W1 = (const float*)d_in[8];
  const float* b1 = (const float*)d_in[9];
  const float* W2 = (const float*)d_in[10];
  const float* b2 = (const float*)d_in[11];
  float* out = (float*)d_out;

  const int* src = edge;
  const int* dst = edge + N_EDGES;

  char* p = (char*)d_ws;
  auto alloc = [&](size_t bytes) -> void* {
    void* r = (void*)p;
    p += (bytes + 255) & ~(size_t)255;
    return r;
  };
  int* cnt = (int*)alloc(N_NODES * 4);
  int* incl = (int*)alloc(N_NODES * 4);
  int* bsum = (int*)alloc(SCAN_BLK * 4);
  int* boff = (int*)alloc(SCAN_BLK * 4);
  int* row_ptr = (int*)alloc((N_NODES + 1) * 4);
  int* cursor = (int*)alloc(N_NODES * 4);
  int* col = (int*)alloc(N_EDGES * 4);
  float* degf = (float*)alloc(N_NODES * 4);
  ushort_t* W2b = (ushort_t*)alloc((size_t)NLAYERS * 65536 * 2);
  ushort_t* xb0 = (ushort_t*)alloc((size_t)N_NODES * DIM * 2);
  ushort_t* xb_cur = (ushort_t*)alloc((size_t)N_NODES * DIM * 2);
  ushort_t* aggb = (ushort_t*)alloc((size_t)N_NODES * DIM * 2);
  ushort_t* hb = (ushort_t*)alloc((size_t)N_NODES * DIM * 2);
  float* sums_part = (float*)alloc(NPART * 256 * 4);
  float* bnsc = (float*)alloc(2 * DIM * 4);
  float* pooled = (float*)alloc(NGRAPHS * DIM * 4);
  int* gstart = (int*)alloc((NGRAPHS + 1) * 4);

  // ---- CSR build + weight prep + graph bounds + x->bf16 ----
  hipMemsetAsync(cnt, 0, N_NODES * 4, stream);
  hipMemsetAsync(sums_part, 0, NPART * 256 * 4, stream);
  k_count<<<(N_EDGES + 255) / 256, 256, 0, stream>>>(dst, cnt);
  k_scan_a<<<SCAN_NB, SCAN_BLK, 0, stream>>>(cnt, incl, bsum);
  k_scan_b<<<1, SCAN_BLK, 0, stream>>>(bsum, boff);
  k_scan_c<<<SCAN_NB, SCAN_BLK, 0, stream>>>(cnt, incl, boff, row_ptr, cursor, degf);
  k_fill4<<<FILL_GRPS * FILL_BPG, 256, 0, stream>>>(src, dst, cursor, col);
  k_wt2<<<(NLAYERS * 8 * 4 * 128 + 255) / 256, 256, 0, stream>>>(Wl, Wr, W2b);
  k_gbounds<<<1, 128, 0, stream>>>(batch, gstart);
  k_tobf16<<<(N_NODES * DIM / 4 + 255) / 256, 256, 0, stream>>>(x, xb0);

  // ---- layers ----
  const ushort_t* xin = xb0;
  for (int l = 0; l < NLAYERS; ++l) {
    k_gather4<<<(N_NODES + 3) / 4, 256, 0, stream>>>(xin, row_ptr, col, degf, aggb);
    k_mfma3<<<(N_NODES + 63) / 64, 256, 0, stream>>>(
        aggb, xin, W2b + (size_t)l * 65536, bl + (size_t)l * DIM, hb, sums_part);
    k_bnfin<<<1, 128, 0, stream>>>(sums_part, gamma + (size_t)l * DIM,
                                   beta + (size_t)l * DIM, bnsc);
    if (l < NLAYERS - 1) {
      k_bn_apply2<<<(N_NODES * DIM / 4 + 255) / 256, 256, 0, stream>>>(hb, bnsc, xb_cur);
      xin = xb_cur;
    }
  }

  // ---- pool (BN+ReLU fused) + head ----
  hipMemsetAsync(pooled, 0, NGRAPHS * DIM * 4, stream);
  k_pool4<<<NGRAPHS * POOL_CHUNKS, 256, 0, stream>>>(hb, bnsc, gstart, pooled);
  k_head2<<<NGRAPHS, 256, 0, stream>>>(pooled, gstart, W1, b1, W2, b2, out);
}

// Round 19
// 295.489 us; speedup vs baseline: 1.0360x; 1.0360x over previous
//
#include <hip/hip_runtime.h>

#define N_NODES 50000
#define N_EDGES 800000
#define DIM 128
#define NLAYERS 3
#define NCLASSES 6
#define NGRAPHS 64
#define BN_EPS 1e-5f

#define SCAN_BLK 256
#define SCAN_NB ((N_NODES + SCAN_BLK - 1) / SCAN_BLK)  // 196

#define POOL_CHUNKS 8
#define NPART 16

#define FILL_GRPS 8
#define FILL_BPG 128
#define NODES_PER_GRP ((N_NODES + FILL_GRPS - 1) / FILL_GRPS)  // 6250

typedef unsigned short ushort_t;
typedef unsigned int uint_t;
using bf16x8 = __attribute__((ext_vector_type(8))) short;
using f32x4 = __attribute__((ext_vector_type(4))) float;

__device__ __forceinline__ float bf2f(ushort_t b) {
  return __uint_as_float(((uint_t)b) << 16);
}
__device__ __forceinline__ ushort_t f2bf(float f) {  // round-to-nearest-even
  uint_t u = __float_as_uint(f);
  u += 0x7fffu + ((u >> 16) & 1u);
  return (ushort_t)(u >> 16);
}

// ---------------- CSR build ----------------

__global__ void k_count(const int* __restrict__ dst, int* __restrict__ cnt) {
  int e = blockIdx.x * blockDim.x + threadIdx.x;
  if (e < N_EDGES) atomicAdd(&cnt[dst[e]], 1);
}

__global__ void k_scan_a(const int* __restrict__ cnt, int* __restrict__ incl,
                         int* __restrict__ bsum) {
  __shared__ int s[SCAN_BLK];
  int i = blockIdx.x * SCAN_BLK + threadIdx.x;
  int v = (i < N_NODES) ? cnt[i] : 0;
  s[threadIdx.x] = v;
  __syncthreads();
  for (int off = 1; off < SCAN_BLK; off <<= 1) {
    int t = (threadIdx.x >= off) ? s[threadIdx.x - off] : 0;
    __syncthreads();
    s[threadIdx.x] += t;
    __syncthreads();
  }
  if (i < N_NODES) incl[i] = s[threadIdx.x];
  if (threadIdx.x == SCAN_BLK - 1) bsum[blockIdx.x] = s[SCAN_BLK - 1];
}

__global__ void k_scan_b(const int* __restrict__ bsum, int* __restrict__ boff) {
  __shared__ int s[SCAN_BLK];
  int t = threadIdx.x;
  int v = (t < SCAN_NB) ? bsum[t] : 0;
  s[t] = v;
  __syncthreads();
  for (int off = 1; off < SCAN_BLK; off <<= 1) {
    int u = (t >= off) ? s[t - off] : 0;
    __syncthreads();
    s[t] += u;
    __syncthreads();
  }
  boff[t] = s[t] - v;
}

__global__ void k_scan_c(const int* __restrict__ cnt, const int* __restrict__ incl,
                         const int* __restrict__ boff, int* __restrict__ row_ptr,
                         int* __restrict__ cursor, float* __restrict__ degf) {
  int i = blockIdx.x * SCAN_BLK + threadIdx.x;
  if (i < N_NODES) {
    int ex = incl[i] - cnt[i] + boff[blockIdx.x];
    row_ptr[i] = ex;
    cursor[i] = ex;
    degf[i] = (float)max(cnt[i], 1);
  }
  if (i == 0) row_ptr[N_NODES] = N_EDGES;
}

// group-partitioned fill (round-8 structure; fastest measured variant)
__global__ void k_fill2(const int* __restrict__ src, const int* __restrict__ dst,
                        int* __restrict__ cursor, int* __restrict__ col) {
  int grp = blockIdx.x & (FILL_GRPS - 1);
  int blk = blockIdx.x >> 3;
  int lo = grp * NODES_PER_GRP;
  int hi = min(lo + NODES_PER_GRP, N_NODES);
  int per = (N_EDGES + FILL_BPG - 1) / FILL_BPG;  // 6250
  int es = blk * per, ee = min(es + per, N_EDGES);
  for (int e = es + (int)threadIdx.x; e < ee; e += (int)blockDim.x) {
    int d = dst[e];
    if (d >= lo && d < hi) {
      int pos = atomicAdd(&cursor[d], 1);
      col[pos] = src[e];
    }
  }
}

// ---------------- weight prep: split hi/lo bf16, frag-order permute ----------------
// W2 layout (ushort): [l][kstep 0..7][part 0..1][q 0..3][c 0..127][kk8 0..7]
__global__ void k_wt2(const float* __restrict__ Wl, const float* __restrict__ Wr,
                      ushort_t* __restrict__ W2) {
  int i = blockIdx.x * blockDim.x + threadIdx.x;  // 3*8*4*128 = 12288
  if (i >= NLAYERS * 8 * 4 * 128) return;
  int c = i & 127;
  int q = (i >> 7) & 3;
  int ks = (i >> 9) & 7;
  int l = i >> 12;
  int kbase = ks * 32 + q * 8;
  size_t obase = (size_t)l * 65536 + ks * 8192 + q * 1024 + c * 8;
#pragma unroll
  for (int kk = 0; kk < 8; ++kk) {
    int k = kbase + kk;
    float w = (k < DIM) ? Wl[(size_t)l * DIM * DIM + c * DIM + k]
                        : Wr[(size_t)l * DIM * DIM + c * DIM + (k - DIM)];
    ushort_t hi = f2bf(w);
    float lo = w - bf2f(hi);
    W2[obase + kk] = hi;
    W2[obase + 4096 + kk] = f2bf(lo);  // part 1 offset = 4*1024
  }
}

// fp32 -> bf16 convert (input x)
__global__ void k_tobf16(const float* __restrict__ x, ushort_t* __restrict__ xb) {
  int i4 = blockIdx.x * blockDim.x + threadIdx.x;
  if (i4 >= N_NODES * DIM / 4) return;
  float4 v = ((const float4*)x)[i4];
  ushort4 o;
  o.x = f2bf(v.x);
  o.y = f2bf(v.y);
  o.z = f2bf(v.z);
  o.w = f2bf(v.w);
  ((ushort4*)xb)[i4] = o;
}

// ---------------- per-layer kernels ----------------

__device__ __forceinline__ void acc_row(uint4 v, float* a) {
  a[0] += bf2f((ushort_t)(v.x & 0xffffu));
  a[1] += bf2f((ushort_t)(v.x >> 16));
  a[2] += bf2f((ushort_t)(v.y & 0xffffu));
  a[3] += bf2f((ushort_t)(v.y >> 16));
  a[4] += bf2f((ushort_t)(v.z & 0xffffu));
  a[5] += bf2f((ushort_t)(v.z >> 16));
  a[6] += bf2f((ushort_t)(v.w & 0xffffu));
  a[7] += bf2f((ushort_t)(v.w >> 16));
}

// one wave per node; 16 lanes per row (uint4 = 16B), 4 neighbors concurrent;
// predicated 4-deep tail (remainder edges loaded in ONE batched round).
__global__ void k_gather4(const ushort_t* __restrict__ xb, const int* __restrict__ row_ptr,
                          const int* __restrict__ col, const float* __restrict__ degf,
                          ushort_t* __restrict__ aggb) {
  int wid = threadIdx.x >> 6, lane = threadIdx.x & 63;
  int n = blockIdx.x * 4 + wid;
  if (n >= N_NODES) return;
  int beg = row_ptr[n], end = row_ptr[n + 1];
  int sub = lane >> 4;  // 0..3: neighbor sub-stream
  int c16 = lane & 15;  // uint4 index within row
  const uint4* x4 = (const uint4*)xb;
  float a[8] = {0.f, 0.f, 0.f, 0.f, 0.f, 0.f, 0.f, 0.f};
  int p = beg + sub;
  for (; p + 12 < end; p += 16) {
    int c[4];
#pragma unroll
    for (int u = 0; u < 4; ++u) c[u] = col[p + 4 * u];
    uint4 v[4];
#pragma unroll
    for (int u = 0; u < 4; ++u) v[u] = x4[(size_t)c[u] * 16 + c16];
#pragma unroll
    for (int u = 0; u < 4; ++u) acc_row(v[u], a);
  }
  if (p < end) {  // predicated batched tail: up to 4 loads in flight
    int c[4];
#pragma unroll
    for (int u = 0; u < 4; ++u) {
      int pp = p + 4 * u;
      c[u] = (pp < end) ? col[pp] : -1;
    }
    uint4 v[4];
#pragma unroll
    for (int u = 0; u < 4; ++u) {
      int cc = (c[u] < 0) ? 0 : c[u];
      v[u] = x4[(size_t)cc * 16 + c16];
    }
#pragma unroll
    for (int u = 0; u < 4; ++u)
      if (c[u] >= 0) acc_row(v[u], a);
  }
#pragma unroll
  for (int u = 0; u < 8; ++u) {
    a[u] += __shfl_xor(a[u], 16);
    a[u] += __shfl_xor(a[u], 32);
  }
  if (sub == 0) {
    float inv = 1.0f / degf[n];
    uint4 o;
    o.x = (uint_t)f2bf(a[0] * inv) | ((uint_t)f2bf(a[1] * inv) << 16);
    o.y = (uint_t)f2bf(a[2] * inv) | ((uint_t)f2bf(a[3] * inv) << 16);
    o.z = (uint_t)f2bf(a[4] * inv) | ((uint_t)f2bf(a[5] * inv) << 16);
    o.w = (uint_t)f2bf(a[6] * inv) | ((uint_t)f2bf(a[7] * inv) << 16);
    ((uint4*)aggb)[(size_t)n * 16 + c16] = o;
  }
}

// MFMA GEMM + fused BN stats (round-11 structure: 2 K-steps/stage via regular
// vector loads, per-wave epilogue, shuffle+LDS BN partials, bf16 h output).
__global__ __launch_bounds__(256) void k_mfma3(
    const ushort_t* __restrict__ aggb, const ushort_t* __restrict__ xb,
    const ushort_t* __restrict__ W2l, const float* __restrict__ bl,
    ushort_t* __restrict__ hb, float* __restrict__ sums_part) {
  __shared__ ushort_t Bs[16384];   // 32 KB: two ksteps [kh][part][q][c][8]
  __shared__ float Es[4][16][65];  // 16.6 KB per-wave transpose
  __shared__ float lsums[4][256];  // 4 KB BN partials

  int tid = threadIdx.x;
  int wave = tid >> 6, lane = tid & 63;
  int rw = blockIdx.x * 64 + wave * 16;
  int lr = lane & 15;  // frag row / frag col
  int q = lane >> 4;   // 0..3 (k-chunk)
  int rowA = rw + lr;
  if (rowA > N_NODES - 1) rowA = N_NODES - 1;  // clamp; stores/stats guarded

  f32x4 acc[8];
#pragma unroll
  for (int c = 0; c < 8; ++c) acc[c] = (f32x4){0.f, 0.f, 0.f, 0.f};

#pragma unroll 1
  for (int kp = 0; kp < 4; ++kp) {
    const uint4* wsrc = (const uint4*)(W2l + (size_t)kp * 16384);
#pragma unroll
    for (int it = 0; it < 8; ++it)
      ((uint4*)Bs)[it * 256 + tid] = wsrc[it * 256 + tid];
    __syncthreads();
#pragma unroll
    for (int kh = 0; kh < 2; ++kh) {
      int ks = kp * 2 + kh;
      const ushort_t* Asrc = (ks < 4) ? aggb : xb;
      int koff = (ks & 3) * 32 + q * 8;
      bf16x8 af = *(const bf16x8*)(Asrc + (size_t)rowA * DIM + koff);
      const ushort_t* bbase = Bs + kh * 8192 + q * 1024;
#pragma unroll
      for (int cf = 0; cf < 8; ++cf) {
        int ci = cf * 16 + lr;
        bf16x8 bh = *(const bf16x8*)(bbase + ci * 8);
        bf16x8 bo = *(const bf16x8*)(bbase + 4096 + ci * 8);
        acc[cf] = __builtin_amdgcn_mfma_f32_16x16x32_bf16(af, bh, acc[cf], 0, 0, 0);
        acc[cf] = __builtin_amdgcn_mfma_f32_16x16x32_bf16(af, bo, acc[cf], 0, 0, 0);
      }
    }
    __syncthreads();
  }

  // epilogue: per-wave transpose -> bf16 store + column stats
  float ts[2][4] = {{0.f, 0.f, 0.f, 0.f}, {0.f, 0.f, 0.f, 0.f}};
  float tq[2][4] = {{0.f, 0.f, 0.f, 0.f}, {0.f, 0.f, 0.f, 0.f}};
#pragma unroll
  for (int colhalf = 0; colhalf < 2; ++colhalf) {
#pragma unroll
    for (int cf2 = 0; cf2 < 4; ++cf2) {
      f32x4 a = acc[colhalf * 4 + cf2];
#pragma unroll
      for (int i = 0; i < 4; ++i) Es[wave][q * 4 + i][cf2 * 16 + lr] = a[i];
    }
#pragma unroll
    for (int it = 0; it < 4; ++it) {
      int idx = it * 64 + lane;
      int r = idx >> 4, c4 = idx & 15;
      int n = rw + r;
      if (n < N_NODES) {
        int j = colhalf * 64 + c4 * 4;
        float4 v = *(float4*)&Es[wave][r][c4 * 4];
        v.x += bl[j];
        v.y += bl[j + 1];
        v.z += bl[j + 2];
        v.w += bl[j + 3];
        ts[colhalf][0] += v.x;
        ts[colhalf][1] += v.y;
        ts[colhalf][2] += v.z;
        ts[colhalf][3] += v.w;
        tq[colhalf][0] += v.x * v.x;
        tq[colhalf][1] += v.y * v.y;
        tq[colhalf][2] += v.z * v.z;
        tq[colhalf][3] += v.w * v.w;
        ushort4 o;
        o.x = f2bf(v.x);
        o.y = f2bf(v.y);
        o.z = f2bf(v.z);
        o.w = f2bf(v.w);
        *(ushort4*)(hb + (size_t)n * DIM + j) = o;
      }
    }
  }
  // BN partials: q-group shuffle reduce -> plain LDS -> 256 atomics/block
#pragma unroll
  for (int ch = 0; ch < 2; ++ch)
#pragma unroll
    for (int u = 0; u < 4; ++u) {
      ts[ch][u] += __shfl_xor(ts[ch][u], 16);
      ts[ch][u] += __shfl_xor(ts[ch][u], 32);
      tq[ch][u] += __shfl_xor(tq[ch][u], 16);
      tq[ch][u] += __shfl_xor(tq[ch][u], 32);
    }
  if (lane < 16) {
#pragma unroll
    for (int ch = 0; ch < 2; ++ch)
#pragma unroll
      for (int u = 0; u < 4; ++u) {
        int j = ch * 64 + lr * 4 + u;
        lsums[wave][j] = ts[ch][u];
        lsums[wave][128 + j] = tq[ch][u];
      }
  }
  __syncthreads();
  float tot = lsums[0][tid] + lsums[1][tid] + lsums[2][tid] + lsums[3][tid];
  atomicAdd(&sums_part[(blockIdx.x & (NPART - 1)) * 256 + tid], tot);
}

// fold partitioned BN sums into scale/shift; self-clear sums_part for next layer
__global__ void k_bnfin(float* __restrict__ sums_part, const float* __restrict__ gamma,
                        const float* __restrict__ beta, float* __restrict__ bnsc) {
  int j = threadIdx.x;  // 128
  float s = 0.f, q = 0.f;
  for (int p = 0; p < NPART; ++p) {
    s += sums_part[p * 256 + j];
    q += sums_part[p * 256 + 128 + j];
    sums_part[p * 256 + j] = 0.f;
    sums_part[p * 256 + 128 + j] = 0.f;
  }
  float mu = s * (1.0f / N_NODES);
  float var = q * (1.0f / N_NODES) - mu * mu;
  float sc = gamma[j] * rsqrtf(var + BN_EPS);
  bnsc[j] = sc;
  bnsc[128 + j] = beta[j] - mu * sc;
}

// normalize + relu: bf16 h -> bf16 x
__global__ void k_bn_apply2(const ushort_t* __restrict__ hb, const float* __restrict__ bnsc,
                            ushort_t* __restrict__ xb) {
  int i4 = blockIdx.x * blockDim.x + threadIdx.x;
  if (i4 >= N_NODES * DIM / 4) return;
  int j0 = (i4 * 4) & (DIM - 1);
  ushort4 v = ((const ushort4*)hb)[i4];
  float o[4] = {bf2f(v.x), bf2f(v.y), bf2f(v.z), bf2f(v.w)};
  ushort4 r;
#pragma unroll
  for (int u = 0; u < 4; ++u) {
    int j = j0 + u;
    o[u] = fmaxf(fmaf(o[u], bnsc[j], bnsc[128 + j]), 0.f);
  }
  r.x = f2bf(o[0]);
  r.y = f2bf(o[1]);
  r.z = f2bf(o[2]);
  r.w = f2bf(o[3]);
  ((ushort4*)xb)[i4] = r;
}

// ---------------- pooling + head ----------------

__global__ void k_gbounds(const int* __restrict__ batch, int* __restrict__ gstart) {
  int t = threadIdx.x;
  if (t > NGRAPHS) return;
  if (t == NGRAPHS) {
    gstart[NGRAPHS] = N_NODES;
    return;
  }
  int lo = 0, hi = N_NODES;
  while (lo < hi) {
    int mid = (lo + hi) >> 1;
    if (batch[mid] < t) lo = mid + 1;
    else hi = mid;
  }
  gstart[t] = lo;
}

// pool over the LAST layer from bf16 h + bnsc (BN+ReLU fused in).
__global__ void k_pool4(const ushort_t* __restrict__ hb, const float* __restrict__ bnsc,
                        const int* __restrict__ gstart, float* __restrict__ pooled) {
  int g = blockIdx.x >> 3;
  int ck = blockIdx.x & 7;
  int s = gstart[g], e = gstart[g + 1];
  int len = e - s;
  int per = (len + POOL_CHUNKS - 1) / POOL_CHUNKS;
  int rs = s + ck * per;
  int re = min(rs + per, e);
  int j2 = threadIdx.x & 63;  // uint (2 feats)
  int rg = threadIdx.x >> 6;  // 0..3
  const uint_t* h1 = (const uint_t*)hb;
  float sc0 = bnsc[2 * j2], sh0 = bnsc[128 + 2 * j2];
  float sc1 = bnsc[2 * j2 + 1], sh1 = bnsc[128 + 2 * j2 + 1];
  float ax = 0.f, ay = 0.f;
  for (int r = rs + rg; r < re; r += 4) {
    uint_t v = h1[(size_t)r * 64 + j2];
    ax += fmaxf(fmaf(bf2f((ushort_t)(v & 0xffffu)), sc0, sh0), 0.f);
    ay += fmaxf(fmaf(bf2f((ushort_t)(v >> 16)), sc1, sh1), 0.f);
  }
  __shared__ float sred[4][DIM];
  sred[rg][2 * j2] = ax;
  sred[rg][2 * j2 + 1] = ay;
  __syncthreads();
  if (rg < 2) {
    int j = rg * 64 + j2;
    float v = sred[0][j] + sred[1][j] + sred[2][j] + sred[3][j];
    atomicAdd(&pooled[g * DIM + j], v);
  }
}

// one block per graph: pm staged in LDS; shuffle-reduce MLP head.
__global__ void k_head2(const float* __restrict__ pooled, const int* __restrict__ gstart,
                        const float* __restrict__ W1, const float* __restrict__ b1,
                        const float* __restrict__ W2, const float* __restrict__ b2,
                        float* __restrict__ out) {
  int g = blockIdx.x;
  int tid = threadIdx.x;
  __shared__ float pm[DIM];
  __shared__ float hid[64];
  float inv = 1.0f / fmaxf((float)(gstart[g + 1] - gstart[g]), 1.0f);
  if (tid < DIM) pm[tid] = pooled[g * DIM + tid] * inv;
  __syncthreads();
  {
    int m = tid >> 2, part = tid & 3;
    const float* w = W1 + m * DIM + part * 32;
    const float* pp = pm + part * 32;
    float acc = 0.f;
#pragma unroll
    for (int k = 0; k < 32; ++k) acc += pp[k] * w[k];
    acc += __shfl_down(acc, 1);
    acc += __shfl_down(acc, 2);
    if (part == 0) hid[m] = fmaxf(acc + b1[m], 0.f);
  }
  __syncthreads();
  if (tid < NCLASSES * 8) {
    int c = tid >> 3, pp8 = tid & 7;
    const float* w = W2 + c * 64 + pp8 * 8;
    const float* hh = hid + pp8 * 8;
    float acc = 0.f;
#pragma unroll
    for (int k = 0; k < 8; ++k) acc += hh[k] * w[k];
    acc += __shfl_down(acc, 1);
    acc += __shfl_down(acc, 2);
    acc += __shfl_down(acc, 4);
    if (pp8 == 0) out[g * NCLASSES + c] = acc + b2[c];
  }
}

// ---------------- launch ----------------

extern "C" void kernel_launch(void* const* d_in, const int* in_sizes, int n_in,
                              void* d_out, int out_size, void* d_ws, size_t ws_size,
                              hipStream_t stream) {
  const float* x = (const float*)d_in[0];
  const int* edge = (const int*)d_in[1];
  const int* batch = (const int*)d_in[2];
  const float* Wl = (const float*)d_in[3];
  const float* bl = (const float*)d_in[4];
  const float* Wr = (const float*)d_in[5];
  const float* gamma = (const float*)d_in[6];
  const float* beta = (const float*)d_in[7];
  const float* W1 = (const float*)d_in[8];
  const float* b1 = (const float*)d_in[9];
  const float* W2 = (const float*)d_in[10];
  const float* b2 = (const float*)d_in[11];
  float* out = (float*)d_out;

  const int* src = edge;
  const int* dst = edge + N_EDGES;

  char* p = (char*)d_ws;
  auto alloc = [&](size_t bytes) -> void* {
    void* r = (void*)p;
    p += (bytes + 255) & ~(size_t)255;
    return r;
  };
  int* cnt = (int*)alloc(N_NODES * 4);
  int* incl = (int*)alloc(N_NODES * 4);
  int* bsum = (int*)alloc(SCAN_BLK * 4);
  int* boff = (int*)alloc(SCAN_BLK * 4);
  int* row_ptr = (int*)alloc((N_NODES + 1) * 4);
  int* cursor = (int*)alloc(N_NODES * 4);
  int* col = (int*)alloc(N_EDGES * 4);
  float* degf = (float*)alloc(N_NODES * 4);
  ushort_t* W2b = (ushort_t*)alloc((size_t)NLAYERS * 65536 * 2);
  ushort_t* xb0 = (ushort_t*)alloc((size_t)N_NODES * DIM * 2);
  ushort_t* xb_cur = (ushort_t*)alloc((size_t)N_NODES * DIM * 2);
  ushort_t* aggb = (ushort_t*)alloc((size_t)N_NODES * DIM * 2);
  ushort_t* hb = (ushort_t*)alloc((size_t)N_NODES * DIM * 2);
  float* sums_part = (float*)alloc(NPART * 256 * 4);
  float* bnsc = (float*)alloc(2 * DIM * 4);
  float* pooled = (float*)alloc(NGRAPHS * DIM * 4);
  int* gstart = (int*)alloc((NGRAPHS + 1) * 4);

  // ---- CSR build + weight prep + graph bounds + x->bf16 ----
  hipMemsetAsync(cnt, 0, N_NODES * 4, stream);
  hipMemsetAsync(sums_part, 0, NPART * 256 * 4, stream);
  k_count<<<(N_EDGES + 255) / 256, 256, 0, stream>>>(dst, cnt);
  k_scan_a<<<SCAN_NB, SCAN_BLK, 0, stream>>>(cnt, incl, bsum);
  k_scan_b<<<1, SCAN_BLK, 0, stream>>>(bsum, boff);
  k_scan_c<<<SCAN_NB, SCAN_BLK, 0, stream>>>(cnt, incl, boff, row_ptr, cursor, degf);
  k_fill2<<<FILL_GRPS * FILL_BPG, 256, 0, stream>>>(src, dst, cursor, col);
  k_wt2<<<(NLAYERS * 8 * 4 * 128 + 255) / 256, 256, 0, stream>>>(Wl, Wr, W2b);
  k_gbounds<<<1, 128, 0, stream>>>(batch, gstart);
  k_tobf16<<<(N_NODES * DIM / 4 + 255) / 256, 256, 0, stream>>>(x, xb0);

  // ---- layers ----
  const ushort_t* xin = xb0;
  for (int l = 0; l < NLAYERS; ++l) {
    k_gather4<<<(N_NODES + 3) / 4, 256, 0, stream>>>(xin, row_ptr, col, degf, aggb);
    k_mfma3<<<(N_NODES + 63) / 64, 256, 0, stream>>>(
        aggb, xin, W2b + (size_t)l * 65536, bl + (size_t)l * DIM, hb, sums_part);
    k_bnfin<<<1, 128, 0, stream>>>(sums_part, gamma + (size_t)l * DIM,
                                   beta + (size_t)l * DIM, bnsc);
    if (l < NLAYERS - 1) {
      k_bn_apply2<<<(N_NODES * DIM / 4 + 255) / 256, 256, 0, stream>>>(hb, bnsc, xb_cur);
      xin = xb_cur;
    }
  }

  // ---- pool (BN+ReLU fused) + head ----
  hipMemsetAsync(pooled, 0, NGRAPHS * DIM * 4, stream);
  k_pool4<<<NGRAPHS * POOL_CHUNKS, 256, 0, stream>>>(hb, bnsc, gstart, pooled);
  k_head2<<<NGRAPHS, 256, 0, stream>>>(pooled, gstart, W1, b1, W2, b2, out);
}